// Round 6
// baseline (134.468 us; speedup 1.0000x reference)
//
#include <hip/hip_runtime.h>
#include <math.h>

// Problem constants (match reference)
constexpr int   B       = 2048;
constexpr int   P       = 4;
constexpr int   D       = 256;       // K of the GEMM
constexpr int   NNEG    = 32768;
constexpr int   NTILES  = NNEG / 64; // per-row exp2-sum partials (64-col patches)
constexpr float TEMP    = 0.05f;
constexpr float ALPHA   = 0.1f;
constexpr float EPS     = 1e-12f;
constexpr float INV_T   = 1.0f / TEMP;
// A-side rows are pre-scaled by (1/T)*log2(e) so the MFMA accumulator is
// directly q = sim/T * log2(e), and exp(sim/T) = exp2(q).  |q| <= ~30 so no
// max-tracking is needed, and 28.85 << 448 (fp8 e4m3 max) so the scale is
// fp8-safe; fp relative precision is scale-invariant.
constexpr float SCALE_Q = 28.853900817779268f;

typedef float f32x4 __attribute__((ext_vector_type(4)));
typedef int   i32x8 __attribute__((ext_vector_type(8)));

// fp32 -> bf16 (RNE), bit-level
__device__ inline unsigned short f2bf(float f) {
  unsigned int u = __float_as_uint(f);
  u = (u + 0x7fffu + ((u >> 16) & 1u)) >> 16;
  return (unsigned short)u;
}
// bf16 bits -> fp32
__device__ inline float bf2f(unsigned short u) {
  return __uint_as_float((unsigned int)u << 16);
}

// Full 16-lane-row sum via 4 ROW_ROR DPP steps (VALU pipe only, no LDS).
// DPP ctrl must be a LITERAL constant: 0x121=ror1, 0x122=ror2, 0x124=ror4,
// 0x128=ror8.  (Verified working in round 5.)
__device__ inline float ror16_add(float v) {
  int x;
  x = __builtin_amdgcn_update_dpp(0, __float_as_int(v), 0x121, 0xf, 0xf, true);
  v += __int_as_float(x);
  x = __builtin_amdgcn_update_dpp(0, __float_as_int(v), 0x122, 0xf, 0xf, true);
  v += __int_as_float(x);
  x = __builtin_amdgcn_update_dpp(0, __float_as_int(v), 0x124, 0xf, 0xf, true);
  v += __int_as_float(x);
  x = __builtin_amdgcn_update_dpp(0, __float_as_int(v), 0x128, 0xf, 0xf, true);
  v += __int_as_float(x);
  return v;
}

// ---------------------------------------------------------------------------
// FP8 LANE-MAJOR layout: element (row, k) of a [R x 256] fp8 matrix is at
// BYTE index  p*4096 + h*2048 + t*512 + r*32 + b
// where p=row>>4 (16-row panel, 4096 B contiguous), r=row&15, h=k>>7
// (K=128 half), t=(k>>5)&3 (lane k-group), b=k&31.
// MFMA 16x16x128 lane l = r + 16t reads its 32 operand bytes CONTIGUOUSLY at
// half_base + l*32 (since t*512 + r*32 == l*32).  A and B use the identical
// (row,k)->byte bijection, so the MFMA pairs A/B k-positions consistently and
// the dot product is exact for any internal HW byte->k mapping (verified
// absmax 0.0 in rounds 3 and 5).
// ---------------------------------------------------------------------------

// ---------------------------------------------------------------------------
// Kernel 1 (fused prep) — UNCHANGED from the verified round-5 version.
// ---------------------------------------------------------------------------
constexpr int NPANEL = (B + NNEG) / 16;      // 2176
constexpr int LSTR   = 264;                  // LDS row stride in ushorts

__global__ __launch_bounds__(256) void prep_kernel(
    const float* __restrict__ a,
    const float* __restrict__ pzx,
    const float* __restrict__ n,
    unsigned char* __restrict__ a_f8,
    unsigned char* __restrict__ n_f8,
    float* __restrict__ pos_sim,
    float* __restrict__ loss_acc,
    unsigned int* __restrict__ ticket) {
  if (blockIdx.x == 0 && threadIdx.x == 0) { *loss_acc = 0.0f; *ticket = 0u; }
  const int id   = blockIdx.x;
  const int tid  = threadIdx.x;
  const int wave = tid >> 6;
  const int lane = tid & 63;

  if (id < NPANEL) {
    __shared__ __align__(16) unsigned short sm[16 * LSTR];
    const float* src; unsigned char* dst; int prow; float post;
    if (id < B / 16) { src = a; dst = a_f8; prow = id;          post = SCALE_Q; }
    else             { src = n; dst = n_f8; prow = id - B / 16; post = 1.0f; }

    // Phase 1: normalize rows into LDS (bf16).
#pragma unroll
    for (int rr = 0; rr < 4; rr++) {
      const int r = wave * 4 + rr;                       // 0..15
      float4 v = ((const float4*)(src + ((size_t)prow * 16 + r) * D))[lane];
      float ss = v.x * v.x + v.y * v.y + v.z * v.z + v.w * v.w;
#pragma unroll
      for (int off = 32; off > 0; off >>= 1) ss += __shfl_xor(ss, off, 64);
      float inv = post / fmaxf(sqrtf(ss), EPS);
      ushort4 o;
      o.x = f2bf(v.x * inv); o.y = f2bf(v.y * inv);
      o.z = f2bf(v.z * inv); o.w = f2bf(v.w * inv);
      *(ushort4*)&sm[r * LSTR + lane * 4] = o;
    }
    __syncthreads();

    // Phase 2: thread t emits fp8 panel bytes [t*16,+16) as one uint4 store.
    // Byte o: h=o>>11, t2=(o>>9)&3, r=(o>>5)&15, b=o&31; k = h*128+t2*32+b.
    // For o = tid*16: one row r, 16 consecutive k starting at k0.
    const int o  = tid * 16;
    const int r  = (o >> 5) & 15;
    const int k0 = (o >> 11) * 128 + ((o >> 9) & 3) * 32 + (o & 31);
    const unsigned short* s1 = &sm[r * LSTR + k0];   // 16 consecutive bf16
    uint4 ov;
    {
      int w0 = __builtin_amdgcn_cvt_pk_fp8_f32(bf2f(s1[0]),  bf2f(s1[1]),  0,  false);
      w0     = __builtin_amdgcn_cvt_pk_fp8_f32(bf2f(s1[2]),  bf2f(s1[3]),  w0, true);
      int w1 = __builtin_amdgcn_cvt_pk_fp8_f32(bf2f(s1[4]),  bf2f(s1[5]),  0,  false);
      w1     = __builtin_amdgcn_cvt_pk_fp8_f32(bf2f(s1[6]),  bf2f(s1[7]),  w1, true);
      int w2 = __builtin_amdgcn_cvt_pk_fp8_f32(bf2f(s1[8]),  bf2f(s1[9]),  0,  false);
      w2     = __builtin_amdgcn_cvt_pk_fp8_f32(bf2f(s1[10]), bf2f(s1[11]), w2, true);
      int w3 = __builtin_amdgcn_cvt_pk_fp8_f32(bf2f(s1[12]), bf2f(s1[13]), 0,  false);
      w3     = __builtin_amdgcn_cvt_pk_fp8_f32(bf2f(s1[14]), bf2f(s1[15]), w3, true);
      ov.x = (unsigned)w0; ov.y = (unsigned)w1;
      ov.z = (unsigned)w2; ov.w = (unsigned)w3;
    }
    *(uint4*)(dst + (size_t)prow * 4096 + tid * 16) = ov;
  } else {
    int pw = (id - NPANEL) * 4 + wave;   // 0..B*P-1
    if (pw >= B * P) return;
    int b = pw >> 2;                     // P == 4
    float4 av = ((const float4*)(a + (size_t)b * D))[lane];
    float4 pv = ((const float4*)(pzx + (size_t)pw * D))[lane];
    float d  = av.x * pv.x + av.y * pv.y + av.z * pv.z + av.w * pv.w;
    float sa = av.x * av.x + av.y * av.y + av.z * av.z + av.w * av.w;
    float sp = pv.x * pv.x + pv.y * pv.y + pv.z * pv.z + pv.w * pv.w;
#pragma unroll
    for (int off = 32; off > 0; off >>= 1) {
      d  += __shfl_xor(d, off, 64);
      sa += __shfl_xor(sa, off, 64);
      sp += __shfl_xor(sp, off, 64);
    }
    if (lane == 0) {
      float inva = 1.0f / fmaxf(sqrtf(sa), EPS);
      float invp = 1.0f / fmaxf(sqrtf(sp), EPS);
      pos_sim[pw] = d * inva * invp * INV_T;
    }
  }
}

// ---------------------------------------------------------------------------
// Kernel 2: MX-scaled fp8 MFMA GEMM, PERSISTENT / BARRIER-FREE / LDS-FREE.
// Round-5 accounting: negsim ~33us = 4.5x its 7.4us MFMA floor; the per-block
// overhead (A re-staging, cold B loads, 3 barriers, only 16 MFMA/wave of
// work) dominated.  This version:
//  * 512 blocks x 512 threads; each block loops over 8 nblk tiles (one
//    resident round: 2 blocks/CU, no inter-block bubbles).
//  * wave tile = 32 rows x 64 cols (mhalf = wave>>2, u = wave&3): the A
//    operand is 4 x 32B/lane register chunks loaded ONCE (loop-invariant) —
//    no LDS, no global_load_lds, no __syncthreads anywhere.
//  * per iteration: 8 B dwordx4 loads -> 16 MFMA -> 32 exp2 + 32 DPP-add ->
//    4 direct dword stores (wave owns full 64-col patches, so part_s keeps
//    the PROVEN NTILES=512 layout with no cross-wave combine).
// Live regs ~ af32 + acc32 + bf32 + addr ~ 114 < 128 at (512,4): no spill.
// L2 locality: xcd = id&7 owns nblk strip [xcd*16, +16) (1 MB N fp8/XCD).
// ---------------------------------------------------------------------------
__global__ __launch_bounds__(512, 4) void negsim_mfma_kernel(
    const unsigned char* __restrict__ Af,   // fp8 lane-major [B][256]
    const unsigned char* __restrict__ Nf,   // fp8 lane-major [NNEG][256]
    float* __restrict__ part_s) {           // [B][NTILES]
  const int tid   = threadIdx.x;
  const int wave  = tid >> 6;   // 0..7
  const int lane  = tid & 63;
  const int mhalf = wave >> 2;  // 0..1 : 32-row half of the 64-row tile
  const int u     = wave & 3;   // 0..3 : 64-col patch of the 256-col tile

  const int id    = blockIdx.x;          // 0..511
  const int xcd   = id & 7;
  const int j     = id >> 3;             // 0..63
  const int mblk  = j >> 1;              // 0..31
  const int nhalf = j & 1;               // 0..1
  const int m0    = mblk * 64;

  // ---- A operand: loop-invariant, 2 m-panels x 2 K-halves, 32 B/lane. ----
  const unsigned char* Ap =
      Af + (size_t)((m0 >> 4) + mhalf * 2) * 4096 + lane * 32;
  i32x8 af[2][2];
#pragma unroll
  for (int mi = 0; mi < 2; mi++)
#pragma unroll
    for (int h = 0; h < 2; h++)
      af[mi][h] = *(const i32x8*)(Ap + (size_t)mi * 4096 + h * 2048);

  const int row_l = m0 + mhalf * 32 + (lane >> 4) * 4;  // + mi*16 + rr

#pragma unroll
  for (int it = 0; it < 8; it++) {
    const int nblk = xcd * 16 + nhalf * 8 + it;          // 0..127, disjoint
    const unsigned char* Bp =
        Nf + (size_t)(nblk * 16 + u * 4) * 4096 + lane * 32;

    f32x4 acc[2][4] = {};
#pragma unroll
    for (int h = 0; h < 2; h++) {
      i32x8 bf[4];
#pragma unroll
      for (int ni = 0; ni < 4; ni++)
        bf[ni] = *(const i32x8*)(Bp + (size_t)ni * 4096 + h * 2048);
#pragma unroll
      for (int mi = 0; mi < 2; mi++)
#pragma unroll
        for (int ni = 0; ni < 4; ni++)
          acc[mi][ni] = __builtin_amdgcn_mfma_scale_f32_16x16x128_f8f6f4(
              af[mi][h], bf[ni], acc[mi][ni],
              0, 0,                       // cbsz/blgp: FP8 e4m3 for A and B
              0, 0x7f7f7f7f,              // scale_a = 1.0 (e8m0 127)
              0, 0x7f7f7f7f);             // scale_b = 1.0
    }

    // Epilogue: C/D layout row = mi*16 + (lane>>4)*4 + rr, col = ni*16 +
    // (lane&15) (shape-determined on gfx950; verified).  64-col sum =
    // 4 exp2-adds across ni + ror16 across the 16-lane row.  Direct store.
#pragma unroll
    for (int mi = 0; mi < 2; mi++) {
#pragma unroll
      for (int rr = 0; rr < 4; rr++) {
        float e = __builtin_amdgcn_exp2f(acc[mi][0][rr]) +
                  __builtin_amdgcn_exp2f(acc[mi][1][rr]) +
                  __builtin_amdgcn_exp2f(acc[mi][2][rr]) +
                  __builtin_amdgcn_exp2f(acc[mi][3][rr]);
        e = ror16_add(e);
        if ((lane & 15) == 0)
          part_s[(size_t)(row_l + mi * 16 + rr) * NTILES + (nblk * 4 + u)] = e;
      }
    }
  }
}

// ---------------------------------------------------------------------------
// Kernel 3: per-anchor loss + final reduce — UNCHANGED from the verified
// version (NTILES=512 layout).
// ---------------------------------------------------------------------------
__global__ void loss_kernel(const float* __restrict__ part_s,
                            const float* __restrict__ pos_sim,
                            const int* __restrict__ counts,
                            float* __restrict__ loss_acc,
                            unsigned int* __restrict__ ticket,
                            float* __restrict__ out) {
  const int tid = threadIdx.x;
  const int b   = blockIdx.x * 16 + (tid >> 4);
  const int sub = tid & 15;
  const float* ps = part_s + (size_t)b * NTILES;
  float s = 0.0f;
#pragma unroll
  for (int i = 0; i < NTILES / 16; i++) s += ps[sub + i * 16];
  s += __shfl_xor(s, 1, 64);
  s += __shfl_xor(s, 2, 64);
  s += __shfl_xor(s, 4, 64);
  s += __shfl_xor(s, 8, 64);   // 16-lane group now holds full S

  float acc = 0.0f;
  if (sub == 0) {
    float L = logf(s);  // neg_lse in natural-log units
    float p0 = pos_sim[b * P + 0], p1 = pos_sim[b * P + 1];
    float p2 = pos_sim[b * P + 2], p3 = pos_sim[b * P + 3];
    int cnt = counts[b];
    float pj[P] = {p0, p1, p2, p3};
#pragma unroll
    for (int jj = 0; jj < P; jj++) {
      if (jj < cnt) {
        float hi = fmaxf(pj[jj], L), lo = fminf(pj[jj], L);
        acc += hi + log1pf(__expf(lo - hi)) - pj[jj];
      }
    }
    float mp = fmaxf(fmaxf(p0, p1), fmaxf(p2, p3));
    float e0 = __expf(p0 - mp), e1 = __expf(p1 - mp);
    float e2 = __expf(p2 - mp), e3 = __expf(p3 - mp);
    float se = e0 + e1 + e2 + e3;
    float wps = (e0 * p0 + e1 * p1 + e2 * p2 + e3 * p3) / se;
    if (cnt > 1) {
      float hi = fmaxf(wps, L), lo = fminf(wps, L);
      acc += ALPHA * (hi + log1pf(__expf(lo - hi)) - wps);
    }
  }
#pragma unroll
  for (int off = 32; off > 0; off >>= 1) acc += __shfl_xor(acc, off, 64);
  __shared__ float sa[4];
  int wid = tid >> 6, lane = tid & 63;
  if (lane == 0) sa[wid] = acc;
  __syncthreads();
  if (tid == 0) {
    atomicAdd(loss_acc, sa[0] + sa[1] + sa[2] + sa[3]);
    __threadfence();
    unsigned int t = atomicAdd(ticket, 1u);
    if (t == (unsigned int)gridDim.x - 1u) {
      float total = atomicAdd(loss_acc, 0.0f);  // atomic read-back
      out[0] = total / (float)B;
    }
  }
}

// ---------------------------------------------------------------------------
extern "C" void kernel_launch(void* const* d_in, const int* in_sizes, int n_in,
                              void* d_out, int out_size, void* d_ws,
                              size_t ws_size, hipStream_t stream) {
  const float* anc    = (const float*)d_in[0];
  const float* pos    = (const float*)d_in[1];
  const float* neg    = (const float*)d_in[2];
  const int*   counts = (const int*)d_in[3];
  float* out = (float*)d_out;

  // Workspace layout: ~12.6 MB (identical to the verified 126us kernel)
  unsigned char* a_f8 = (unsigned char*)d_ws;            // B*D      (0.5 MB)
  unsigned char* n_f8 = a_f8 + (size_t)B * D;            // NNEG*D   (8 MB)
  float* part_s  = (float*)(n_f8 + (size_t)NNEG * D);    // B*NTILES (4 MB)
  float* pos_sim = part_s + (size_t)B * NTILES;          // B*P
  float* loss_acc = pos_sim + B * P;                     // 1
  unsigned int* ticket = (unsigned int*)(loss_acc + 1);  // 1

  // 2176 panel blocks + 2048 possim blocks
  prep_kernel<<<NPANEL + B * P / 4, 256, 0, stream>>>(
      anc, pos, neg, a_f8, n_f8, pos_sim, loss_acc, ticket);

  negsim_mfma_kernel<<<512, 512, 0, stream>>>(a_f8, n_f8, part_s);

  loss_kernel<<<B / 16, 256, 0, stream>>>(part_s, pos_sim, counts,
                                          loss_acc, ticket, out);
}

// Round 7
// 119.787 us; speedup vs baseline: 1.1226x; 1.1226x over previous
//
#include <hip/hip_runtime.h>
#include <math.h>

// Problem constants (match reference)
constexpr int   B       = 2048;
constexpr int   P       = 4;
constexpr int   D       = 256;       // K of the GEMM
constexpr int   NNEG    = 32768;
constexpr int   NTILES  = NNEG / 64; // per-row exp2-sum partials (64-col patches)
constexpr float TEMP    = 0.05f;
constexpr float ALPHA   = 0.1f;
constexpr float EPS     = 1e-12f;
constexpr float INV_T   = 1.0f / TEMP;
// A-side rows are pre-scaled by (1/T)*log2(e) so the MFMA accumulator is
// directly q = sim/T * log2(e), and exp(sim/T) = exp2(q).  |q| <= ~30 so no
// max-tracking is needed, and 28.85 << 448 (fp8 e4m3 max) so the scale is
// fp8-safe; fp relative precision is scale-invariant.
constexpr float SCALE_Q = 28.853900817779268f;

typedef float f32x4 __attribute__((ext_vector_type(4)));
typedef int   i32x8 __attribute__((ext_vector_type(8)));

// fp32 -> bf16 (RNE), bit-level
__device__ inline unsigned short f2bf(float f) {
  unsigned int u = __float_as_uint(f);
  u = (u + 0x7fffu + ((u >> 16) & 1u)) >> 16;
  return (unsigned short)u;
}
// bf16 bits -> fp32
__device__ inline float bf2f(unsigned short u) {
  return __uint_as_float((unsigned int)u << 16);
}

// Full 16-lane-row sum via 4 ROW_ROR DPP steps (VALU pipe only, no LDS).
// DPP ctrl must be a LITERAL constant: 0x121=ror1, 0x122=ror2, 0x124=ror4,
// 0x128=ror8.  (Verified working in round 5.)
__device__ inline float ror16_add(float v) {
  int x;
  x = __builtin_amdgcn_update_dpp(0, __float_as_int(v), 0x121, 0xf, 0xf, true);
  v += __int_as_float(x);
  x = __builtin_amdgcn_update_dpp(0, __float_as_int(v), 0x122, 0xf, 0xf, true);
  v += __int_as_float(x);
  x = __builtin_amdgcn_update_dpp(0, __float_as_int(v), 0x124, 0xf, 0xf, true);
  v += __int_as_float(x);
  x = __builtin_amdgcn_update_dpp(0, __float_as_int(v), 0x128, 0xf, 0xf, true);
  v += __int_as_float(x);
  return v;
}

// ---------------------------------------------------------------------------
// FP8 LANE-MAJOR layout: element (row, k) of a [R x 256] fp8 matrix is at
// BYTE index  p*4096 + h*2048 + t*512 + r*32 + b
// where p=row>>4 (16-row panel, 4096 B contiguous), r=row&15, h=k>>7
// (K=128 half), t=(k>>5)&3 (lane k-group), b=k&31.
// MFMA 16x16x128 lane l = r + 16t reads its 32 operand bytes CONTIGUOUSLY at
// half_base + l*32 (since t*512 + r*32 == l*32).  A and B use the identical
// (row,k)->byte bijection, so the MFMA pairs A/B k-positions consistently and
// the dot product is exact for any internal HW byte->k mapping (verified
// absmax 0.0 in rounds 3, 5, 6).
// ---------------------------------------------------------------------------

// ---------------------------------------------------------------------------
// Kernel 1 (fused prep) — UNCHANGED from the verified round-5/6 version.
// ---------------------------------------------------------------------------
constexpr int NPANEL = (B + NNEG) / 16;      // 2176
constexpr int LSTR   = 264;                  // LDS row stride in ushorts

__global__ __launch_bounds__(256) void prep_kernel(
    const float* __restrict__ a,
    const float* __restrict__ pzx,
    const float* __restrict__ n,
    unsigned char* __restrict__ a_f8,
    unsigned char* __restrict__ n_f8,
    float* __restrict__ pos_sim,
    float* __restrict__ loss_acc,
    unsigned int* __restrict__ ticket) {
  if (blockIdx.x == 0 && threadIdx.x == 0) { *loss_acc = 0.0f; *ticket = 0u; }
  const int id   = blockIdx.x;
  const int tid  = threadIdx.x;
  const int wave = tid >> 6;
  const int lane = tid & 63;

  if (id < NPANEL) {
    __shared__ __align__(16) unsigned short sm[16 * LSTR];
    const float* src; unsigned char* dst; int prow; float post;
    if (id < B / 16) { src = a; dst = a_f8; prow = id;          post = SCALE_Q; }
    else             { src = n; dst = n_f8; prow = id - B / 16; post = 1.0f; }

    // Phase 1: normalize rows into LDS (bf16).
#pragma unroll
    for (int rr = 0; rr < 4; rr++) {
      const int r = wave * 4 + rr;                       // 0..15
      float4 v = ((const float4*)(src + ((size_t)prow * 16 + r) * D))[lane];
      float ss = v.x * v.x + v.y * v.y + v.z * v.z + v.w * v.w;
#pragma unroll
      for (int off = 32; off > 0; off >>= 1) ss += __shfl_xor(ss, off, 64);
      float inv = post / fmaxf(sqrtf(ss), EPS);
      ushort4 o;
      o.x = f2bf(v.x * inv); o.y = f2bf(v.y * inv);
      o.z = f2bf(v.z * inv); o.w = f2bf(v.w * inv);
      *(ushort4*)&sm[r * LSTR + lane * 4] = o;
    }
    __syncthreads();

    // Phase 2: thread t emits fp8 panel bytes [t*16,+16) as one uint4 store.
    // Byte o: h=o>>11, t2=(o>>9)&3, r=(o>>5)&15, b=o&31; k = h*128+t2*32+b.
    // For o = tid*16: one row r, 16 consecutive k starting at k0.
    const int o  = tid * 16;
    const int r  = (o >> 5) & 15;
    const int k0 = (o >> 11) * 128 + ((o >> 9) & 3) * 32 + (o & 31);
    const unsigned short* s1 = &sm[r * LSTR + k0];   // 16 consecutive bf16
    uint4 ov;
    {
      int w0 = __builtin_amdgcn_cvt_pk_fp8_f32(bf2f(s1[0]),  bf2f(s1[1]),  0,  false);
      w0     = __builtin_amdgcn_cvt_pk_fp8_f32(bf2f(s1[2]),  bf2f(s1[3]),  w0, true);
      int w1 = __builtin_amdgcn_cvt_pk_fp8_f32(bf2f(s1[4]),  bf2f(s1[5]),  0,  false);
      w1     = __builtin_amdgcn_cvt_pk_fp8_f32(bf2f(s1[6]),  bf2f(s1[7]),  w1, true);
      int w2 = __builtin_amdgcn_cvt_pk_fp8_f32(bf2f(s1[8]),  bf2f(s1[9]),  0,  false);
      w2     = __builtin_amdgcn_cvt_pk_fp8_f32(bf2f(s1[10]), bf2f(s1[11]), w2, true);
      int w3 = __builtin_amdgcn_cvt_pk_fp8_f32(bf2f(s1[12]), bf2f(s1[13]), 0,  false);
      w3     = __builtin_amdgcn_cvt_pk_fp8_f32(bf2f(s1[14]), bf2f(s1[15]), w3, true);
      ov.x = (unsigned)w0; ov.y = (unsigned)w1;
      ov.z = (unsigned)w2; ov.w = (unsigned)w3;
    }
    *(uint4*)(dst + (size_t)prow * 4096 + tid * 16) = ov;
  } else {
    int pw = (id - NPANEL) * 4 + wave;   // 0..B*P-1
    if (pw >= B * P) return;
    int b = pw >> 2;                     // P == 4
    float4 av = ((const float4*)(a + (size_t)b * D))[lane];
    float4 pv = ((const float4*)(pzx + (size_t)pw * D))[lane];
    float d  = av.x * pv.x + av.y * pv.y + av.z * pv.z + av.w * pv.w;
    float sa = av.x * av.x + av.y * av.y + av.z * av.z + av.w * av.w;
    float sp = pv.x * pv.x + pv.y * pv.y + pv.z * pv.z + pv.w * pv.w;
#pragma unroll
    for (int off = 32; off > 0; off >>= 1) {
      d  += __shfl_xor(d, off, 64);
      sa += __shfl_xor(sa, off, 64);
      sp += __shfl_xor(sp, off, 64);
    }
    if (lane == 0) {
      float inva = 1.0f / fmaxf(sqrtf(sa), EPS);
      float invp = 1.0f / fmaxf(sqrtf(sp), EPS);
      pos_sim[pw] = d * inva * invp * INV_T;
    }
  }
}

// ---------------------------------------------------------------------------
// Kernel 2: MX-scaled fp8 MFMA GEMM, PERSISTENT with the register-safe r3/r5
// ingredients.  Round-6 post-mortem: full 8-it unroll + af[2][2] in regs ->
// 64/64 arch/acc split -> 13 MB scratch spill; and the 32-row wave tile
// doubled B L2 traffic (both mhalf waves loaded the same panels).
// This version:
//  * 512 blocks x 512 threads; block = (mblk = id>>4) x (ngroup = id&15);
//    it-loop over 8 x 256-col strips (persistent; blocks on the same XCD
//    share their B strips: ids = g mod 16 are = g mod 8 -> same XCD).
//  * wave tile 64 rows x 32 cols (mi=4, ni=2): acc = 32; waves own DISJOINT
//    panels -> B L2 traffic 256 MB total (~7.4us floor, = MFMA floor).
//  * A staged to LDS ONCE per block (16 KB, amortized over 128 MFMA/wave);
//    af read per (mi,h) as one 32-B chunk -- never a 32-reg array.
//  * h-granular copy-free bfA/bfB ping-pong (16+16 regs): phase p+1's 2
//    i32x8 loads issue before phase p's 8 MFMAs.
//  * #pragma unroll 1 on the it-loop: keeps the scheduler's live-range
//    window to one iteration (the r6 spill was hoisting across epilogues).
//  * per-it 2 KB LDS pair-combine (proven r3) -> part_s keeps the verified
//    NTILES=512 64-col layout; workspace stays 12.6 MB.
// Peak live ~ acc32 + bfA16 + bfB16 + af8 + addr ~ 90 < 128 at (512,4).
// ---------------------------------------------------------------------------
__global__ __launch_bounds__(512, 4) void negsim_mfma_kernel(
    const unsigned char* __restrict__ Af,   // fp8 lane-major [B][256]
    const unsigned char* __restrict__ Nf,   // fp8 lane-major [NNEG][256]
    float* __restrict__ part_s) {           // [B][NTILES]
  __shared__ __align__(16) unsigned char As[4 * 4096];  // 16 KB (4 panels)
  __shared__ float part_l[8][64];                       // 2 KB combine buffer

  const int tid  = threadIdx.x;
  const int wave = tid >> 6;   // 0..7 : 32-col patch within the 256-col strip
  const int lane = tid & 63;

  const int id     = blockIdx.x;     // 0..511
  const int ngroup = id & 15;        // 0..15 : 2048-col super-strip (XCD-local)
  const int mblk   = id >> 4;        // 0..31
  const int m0     = mblk * 64;

  // ---- stage A-tile once (16 KB, linear in global AND LDS):
  //      8 waves x 2 instr, each 1 KB. ----
#pragma unroll
  for (int t = 0; t < 2; t++) {
    const int s = wave * 2 + t;
    __builtin_amdgcn_global_load_lds(
        (const __attribute__((address_space(1))) unsigned int*)
            (Af + (size_t)(m0 >> 4) * 4096 + s * 1024 + lane * 16),
        (__attribute__((address_space(3))) unsigned int*)(As + s * 1024 + lane * 16),
        16, 0, 0);
  }

  // Panel base for this wave at iteration it: pn(it) = ngroup*128 + it*16 +
  // wave*2 (each wave owns panels pn, pn+1 = 32 cols; disjoint across waves).
  const unsigned char* Bw = Nf + (size_t)(ngroup * 128 + wave * 2) * 4096 + lane * 32;

  // Prologue: bfA <- (it=0, h=0).
  i32x8 bfA0 = *(const i32x8*)(Bw);
  i32x8 bfA1 = *(const i32x8*)(Bw + 4096);

  __syncthreads();   // drains the A staging

#pragma unroll 1
  for (int it = 0; it < 8; it++) {
    const unsigned char* Bp  = Bw + (size_t)it * 16 * 4096;
    const unsigned char* Bpn = Bw + (size_t)(((it + 1) & 7) * 16) * 4096;

    f32x4 acc[4][2] = {};

    // ---- phase h=0: issue bfB <- (it, h=1); compute with bfA ----
    i32x8 bfB0 = *(const i32x8*)(Bp + 2048);
    i32x8 bfB1 = *(const i32x8*)(Bp + 4096 + 2048);
#pragma unroll
    for (int mi = 0; mi < 4; mi++) {
      i32x8 af = *(const i32x8*)&As[mi * 4096 + lane * 32];
      acc[mi][0] = __builtin_amdgcn_mfma_scale_f32_16x16x128_f8f6f4(
          af, bfA0, acc[mi][0], 0, 0, 0, 0x7f7f7f7f, 0, 0x7f7f7f7f);
      acc[mi][1] = __builtin_amdgcn_mfma_scale_f32_16x16x128_f8f6f4(
          af, bfA1, acc[mi][1], 0, 0, 0, 0x7f7f7f7f, 0, 0x7f7f7f7f);
    }

    // ---- phase h=1: issue bfA <- (it+1, h=0) (wraps on last it; redundant
    //      but valid load); compute with bfB ----
    bfA0 = *(const i32x8*)(Bpn);
    bfA1 = *(const i32x8*)(Bpn + 4096);
#pragma unroll
    for (int mi = 0; mi < 4; mi++) {
      i32x8 af = *(const i32x8*)&As[mi * 4096 + 2048 + lane * 32];
      acc[mi][0] = __builtin_amdgcn_mfma_scale_f32_16x16x128_f8f6f4(
          af, bfB0, acc[mi][0], 0, 0, 0, 0x7f7f7f7f, 0, 0x7f7f7f7f);
      acc[mi][1] = __builtin_amdgcn_mfma_scale_f32_16x16x128_f8f6f4(
          af, bfB1, acc[mi][1], 0, 0, 0, 0x7f7f7f7f, 0, 0x7f7f7f7f);
    }

    // ---- Epilogue.  C/D layout row = mi*16 + (lane>>4)*4 + rr,
    //      col = ni*16+(lane&15) (shape-determined on gfx950; verified).
    //      32-col partial = 2 exp2 adds + ror16; pair-combine to 64-col
    //      slots via 2 KB LDS (proven r3 pattern). ----
#pragma unroll
    for (int mi = 0; mi < 4; mi++) {
#pragma unroll
      for (int rr = 0; rr < 4; rr++) {
        float e = __builtin_amdgcn_exp2f(acc[mi][0][rr]) +
                  __builtin_amdgcn_exp2f(acc[mi][1][rr]);
        e = ror16_add(e);
        if ((lane & 15) == 0)
          part_l[wave][mi * 16 + (lane >> 4) * 4 + rr] = e;
      }
    }
    __syncthreads();
    if (tid < 256) {
      const int u4  = tid >> 6;    // 0..3 : 64-col slot within the strip
      const int row = tid & 63;
      float s64 = part_l[2 * u4][row] + part_l[2 * u4 + 1][row];
      part_s[(size_t)(m0 + row) * NTILES + (ngroup * 32 + it * 4 + u4)] = s64;
    }
    __syncthreads();   // part_l free for next iteration
  }
}

// ---------------------------------------------------------------------------
// Kernel 3: per-anchor loss + final reduce — UNCHANGED from the verified
// version (NTILES=512 layout).
// ---------------------------------------------------------------------------
__global__ void loss_kernel(const float* __restrict__ part_s,
                            const float* __restrict__ pos_sim,
                            const int* __restrict__ counts,
                            float* __restrict__ loss_acc,
                            unsigned int* __restrict__ ticket,
                            float* __restrict__ out) {
  const int tid = threadIdx.x;
  const int b   = blockIdx.x * 16 + (tid >> 4);
  const int sub = tid & 15;
  const float* ps = part_s + (size_t)b * NTILES;
  float s = 0.0f;
#pragma unroll
  for (int i = 0; i < NTILES / 16; i++) s += ps[sub + i * 16];
  s += __shfl_xor(s, 1, 64);
  s += __shfl_xor(s, 2, 64);
  s += __shfl_xor(s, 4, 64);
  s += __shfl_xor(s, 8, 64);   // 16-lane group now holds full S

  float acc = 0.0f;
  if (sub == 0) {
    float L = logf(s);  // neg_lse in natural-log units
    float p0 = pos_sim[b * P + 0], p1 = pos_sim[b * P + 1];
    float p2 = pos_sim[b * P + 2], p3 = pos_sim[b * P + 3];
    int cnt = counts[b];
    float pj[P] = {p0, p1, p2, p3};
#pragma unroll
    for (int jj = 0; jj < P; jj++) {
      if (jj < cnt) {
        float hi = fmaxf(pj[jj], L), lo = fminf(pj[jj], L);
        acc += hi + log1pf(__expf(lo - hi)) - pj[jj];
      }
    }
    float mp = fmaxf(fmaxf(p0, p1), fmaxf(p2, p3));
    float e0 = __expf(p0 - mp), e1 = __expf(p1 - mp);
    float e2 = __expf(p2 - mp), e3 = __expf(p3 - mp);
    float se = e0 + e1 + e2 + e3;
    float wps = (e0 * p0 + e1 * p1 + e2 * p2 + e3 * p3) / se;
    if (cnt > 1) {
      float hi = fmaxf(wps, L), lo = fminf(wps, L);
      acc += ALPHA * (hi + log1pf(__expf(lo - hi)) - wps);
    }
  }
#pragma unroll
  for (int off = 32; off > 0; off >>= 1) acc += __shfl_xor(acc, off, 64);
  __shared__ float sa[4];
  int wid = tid >> 6, lane = tid & 63;
  if (lane == 0) sa[wid] = acc;
  __syncthreads();
  if (tid == 0) {
    atomicAdd(loss_acc, sa[0] + sa[1] + sa[2] + sa[3]);
    __threadfence();
    unsigned int t = atomicAdd(ticket, 1u);
    if (t == (unsigned int)gridDim.x - 1u) {
      float total = atomicAdd(loss_acc, 0.0f);  // atomic read-back
      out[0] = total / (float)B;
    }
  }
}

// ---------------------------------------------------------------------------
extern "C" void kernel_launch(void* const* d_in, const int* in_sizes, int n_in,
                              void* d_out, int out_size, void* d_ws,
                              size_t ws_size, hipStream_t stream) {
  const float* anc    = (const float*)d_in[0];
  const float* pos    = (const float*)d_in[1];
  const float* neg    = (const float*)d_in[2];
  const int*   counts = (const int*)d_in[3];
  float* out = (float*)d_out;

  // Workspace layout: ~12.6 MB (identical to the verified 126us kernel)
  unsigned char* a_f8 = (unsigned char*)d_ws;            // B*D      (0.5 MB)
  unsigned char* n_f8 = a_f8 + (size_t)B * D;            // NNEG*D   (8 MB)
  float* part_s  = (float*)(n_f8 + (size_t)NNEG * D);    // B*NTILES (4 MB)
  float* pos_sim = part_s + (size_t)B * NTILES;          // B*P
  float* loss_acc = pos_sim + B * P;                     // 1
  unsigned int* ticket = (unsigned int*)(loss_acc + 1);  // 1

  // 2176 panel blocks + 2048 possim blocks
  prep_kernel<<<NPANEL + B * P / 4, 256, 0, stream>>>(
      anc, pos, neg, a_f8, n_f8, pos_sim, loss_acc, ticket);

  negsim_mfma_kernel<<<512, 512, 0, stream>>>(a_f8, n_f8, part_s);

  loss_kernel<<<B / 16, 256, 0, stream>>>(part_s, pos_sim, counts,
                                          loss_acc, ticket, out);
}